// Round 15
// baseline (165.353 us; speedup 1.0000x reference)
//
#include <hip/hip_runtime.h>
#include <hip/hip_bf16.h>
#include <math.h>

#define VOCAB 100000
#define TOPK  20
#define EMB   300
#define NTOK  (64*256)
#define NVT   1563          // ceil(VOCAB/64) v-tiles
#define NVGS  96            // v-groups per e-slice; 96%8==0 -> the 5 esl-
                            // siblings of a vg share bid%8 (same XCD L2)

typedef __attribute__((ext_vector_type(8))) short short8;   // 8 bf16 = 4 VGPR
typedef __attribute__((ext_vector_type(4))) float f32x4;

static __device__ inline short f2bf(float f) {
    __hip_bfloat16 h = __float2bfloat16(f);
    short s; __builtin_memcpy(&s, &h, 2);
    return s;
}

// ---------------------------------------------------------------------------
// prep: aT[e][d] = bf16(a[d][e]), zero-padded to 320x320.
// ---------------------------------------------------------------------------
__global__ void prep_kernel(const float* __restrict__ A, short* __restrict__ aT)
{
    const int e = blockIdx.x;                 // 0..319
    for (int d = threadIdx.x; d < 320; d += 256) {
        float f = (e < EMB && d < EMB) ? A[(size_t)d * EMB + e] : 0.f;
        aT[e * 320 + d] = f2bf(f);
    }
}

// ---------------------------------------------------------------------------
// score: s[v] = sum_e tanh( emb[v,:] . a[:,e] ) * b[e]  via bf16 MFMA.
// Persistent B-in-regs structure (r14: VGPR=60 proved ball resident, no
// spill). r14's miss: esl-siblings 102 apart -> different XCDs -> FETCH
// 237MB + L2-miss staging latency exposed between barriers. r15 fixes:
// (1) NVGS=96 (96%8==0): siblings share the XCD, tile fetched into that
//     L2 once, read 5x;
// (2) T14 pf-split: next tile's global loads ISSUED before the k-loop
//     (pf[5][2] regs), WRITTEN to LDS after B2 -- k-loop + barrier cover
//     the (L2-warm) latency.  Regs: ball 40 + pf 44 + acc 16 + misc ~115.
// Block = (esl of 64 e-cols, vg); 8 waves = 2mg x 2ng x 2kh; wave = 32x32,
// K-half 160. Per k-step: 2 A ds_reads + 4 MFMA (B in regs).
// LDS: EsS 40KB + Scr 16KB + Sred = 57.9KB -> 2 blocks/CU.
// ---------------------------------------------------------------------------
__global__ __launch_bounds__(512) void score_kernel(
    const float* __restrict__ emb, const short* __restrict__ aT,
    const float* __restrict__ B, float* __restrict__ Sp)
{
    __shared__ short8 EsS[64 * 40];      // 40960 B : A tile (swizzled)
    __shared__ float4 Scr[16 * 64];      // 16384 B : kh-exchange scratch
    __shared__ float  Sred[128];         // 512 B

    const int bid = blockIdx.x;
    const int esl = bid / NVGS;          // 0..4
    const int vg  = bid % NVGS;          // 0..95

    const int t   = threadIdx.x;
    const int lid = t & 63;
    const int w   = t >> 6;        // 0..7
    const int kh  = w >> 2;        // k-half 0..1
    const int mg  = (w >> 1) & 1;  // m-pair (rows mg*32..mg*32+31)
    const int ng  = w & 1;         // n-pair (cols ng*32..ng*32+31)
    const int lm  = lid & 15;
    const int lk  = lid >> 4;
    const int xm  = lm & 7;        // row%8 == lm%8 (offsets mult of 16)
    const int cell = mg * 2 + ng;  // 0..3

    // ---- B-fragments -> registers ONCE (10 b128 from L2; reused ~16 tiles)
    const short8* aT8 = (const short8*)aT;
    short8 ball[2][5];
    float  bcol[2];
#pragma unroll
    for (int n = 0; n < 2; ++n) {
        const int e = esl * 64 + ng * 32 + n * 16 + lm;
#pragma unroll
        for (int ks = 0; ks < 5; ++ks)
            ball[n][ks] = aT8[e * 40 + kh * 20 + ks * 4 + lk];
        bcol[n] = (e < EMB) ? B[e] : 0.f;
    }
    asm volatile("" ::: "memory");   // pin ball/bcol in regs (no re-load)

    const int rb0 = (mg * 32 + lm) * 40;
    const int rb1 = (mg * 32 + 16 + lm) * 40;

    // zero-pad chunks 38,39 once (never overwritten by staging)
    if (t < 128) {
        const int row = t >> 1, q = 38 + (t & 1);
        EsS[row * 40 + (q ^ (row & 7))] = (short8){0, 0, 0, 0, 0, 0, 0, 0};
    }

    float4 pf[5][2]; float4 pft;

#define ISSUE_PF(V0) do {                                                     \
    const float4* esrc = (const float4*)(emb + (size_t)(V0) * EMB);           \
    _Pragma("unroll")                                                         \
    for (int j = 0; j < 5; ++j) {                                             \
        const int i = t + j * 512;                                            \
        const int row = i / 37, c = i - row * 37;                             \
        const bool ok = (i < 2368) && ((V0) + row < VOCAB);                   \
        pf[j][0] = ok ? esrc[row * 75 + c * 2]     : make_float4(0,0,0,0);    \
        pf[j][1] = ok ? esrc[row * 75 + c * 2 + 1] : make_float4(0,0,0,0);    \
    }                                                                         \
    if (t < 64) pft = ((V0) + t < VOCAB) ? esrc[t * 75 + 74]                  \
                                         : make_float4(0,0,0,0);              \
} while (0)

#define STAGE_WRITE() do {                                                    \
    _Pragma("unroll")                                                         \
    for (int j = 0; j < 5; ++j) {                                             \
        const int i = t + j * 512;                                            \
        if (i < 2368) {                                                       \
            const int row = i / 37, c = i - row * 37;                         \
            short8 val;                                                       \
            val[0] = f2bf(pf[j][0].x); val[1] = f2bf(pf[j][0].y);             \
            val[2] = f2bf(pf[j][0].z); val[3] = f2bf(pf[j][0].w);             \
            val[4] = f2bf(pf[j][1].x); val[5] = f2bf(pf[j][1].y);             \
            val[6] = f2bf(pf[j][1].z); val[7] = f2bf(pf[j][1].w);             \
            EsS[row * 40 + (c ^ (row & 7))] = val;                            \
        }                                                                     \
    }                                                                         \
    if (t < 64) {   /* chunk 37: floats 296..299 + zero pad */                \
        short8 v37 = (short8){0, 0, 0, 0, 0, 0, 0, 0};                        \
        v37[0] = f2bf(pft.x); v37[1] = f2bf(pft.y);                           \
        v37[2] = f2bf(pft.z); v37[3] = f2bf(pft.w);                           \
        EsS[t * 40 + (37 ^ (t & 7))] = v37;                                   \
    }                                                                         \
} while (0)

    const int ntiles = (NVT - vg + NVGS - 1) / NVGS;   // 16 or 17

    ISSUE_PF(vg * 64);               // tile 0 (latency exposed once)
    STAGE_WRITE();
    __syncthreads();                 // B1

    for (int tt = 0; tt < ntiles; ++tt) {
        const int v0   = (vg + tt * NVGS) * 64;
        const bool more = (tt + 1 < ntiles);

        if (more) ISSUE_PF((vg + (tt + 1) * NVGS) * 64);   // T14 issue-early

        // ---- k-loop: 5 steps; 2 A ds_reads + 4 MFMA per step (B in regs)
        f32x4 acc[2][2];
#pragma unroll
        for (int mt = 0; mt < 2; ++mt)
#pragma unroll
            for (int n = 0; n < 2; ++n)
                acc[mt][n] = (f32x4){0.f, 0.f, 0.f, 0.f};
#pragma unroll
        for (int ks = 0; ks < 5; ++ks) {
            const int kx = (kh * 20 + ks * 4 + lk) ^ xm;
            short8 af0 = EsS[rb0 + kx];
            short8 af1 = EsS[rb1 + kx];
            acc[0][0] = __builtin_amdgcn_mfma_f32_16x16x32_bf16(af0, ball[0][ks], acc[0][0], 0, 0, 0);
            acc[0][1] = __builtin_amdgcn_mfma_f32_16x16x32_bf16(af0, ball[1][ks], acc[0][1], 0, 0, 0);
            acc[1][0] = __builtin_amdgcn_mfma_f32_16x16x32_bf16(af1, ball[0][ks], acc[1][0], 0, 0, 0);
            acc[1][1] = __builtin_amdgcn_mfma_f32_16x16x32_bf16(af1, ball[1][ks], acc[1][1], 0, 0, 0);
        }
        __syncthreads();                             // B2: EsS reads done

        // ---- kh=1 ships partials; everyone writes next tile from pf regs
        if (kh == 1) {
#pragma unroll
            for (int mt = 0; mt < 2; ++mt)
#pragma unroll
                for (int n = 0; n < 2; ++n)
                    Scr[((mt * 2 + n) * 4 + cell) * 64 + lid] = *(float4*)&acc[mt][n];
        }
        if (more) STAGE_WRITE();
        __syncthreads();                             // B3: Scr + staging done

        // ---- epilogue (kh=0): combine, tanh, dot b, shfl-reduce
        if (kh == 0) {
            float part[2][4];
#pragma unroll
            for (int mt = 0; mt < 2; ++mt) {
                float4 o0 = Scr[((mt * 2 + 0) * 4 + cell) * 64 + lid];
                float4 o1 = Scr[((mt * 2 + 1) * 4 + cell) * 64 + lid];
#pragma unroll
                for (int i = 0; i < 4; ++i) {
                    float x0 = acc[mt][0][i] + (&o0.x)[i];
                    float x1 = acc[mt][1][i] + (&o1.x)[i];
                    float c0 = fminf(fmaxf(x0, -15.f), 15.f);
                    float c1 = fminf(fmaxf(x1, -15.f), 15.f);
                    float e0 = __expf(2.f * c0);
                    float e1 = __expf(2.f * c1);
                    part[mt][i] = __fdividef(e0 - 1.f, e0 + 1.f) * bcol[0]
                                + __fdividef(e1 - 1.f, e1 + 1.f) * bcol[1];
                }
            }
#pragma unroll
            for (int m = 1; m <= 8; m <<= 1)
#pragma unroll
                for (int mt = 0; mt < 2; ++mt)
#pragma unroll
                    for (int i = 0; i < 4; ++i)
                        part[mt][i] += __shfl_xor(part[mt][i], m);
            if (lm == 0) {
#pragma unroll
                for (int mt = 0; mt < 2; ++mt)
#pragma unroll
                    for (int i = 0; i < 4; ++i)
                        Sred[ng * 64 + mg * 32 + mt * 16 + lk * 4 + i] = part[mt][i];
            }
        }
        __syncthreads();                             // B4: Sred ready

        if (t < 64) {
            const int v = v0 + t;
            if (v < VOCAB) Sp[(size_t)esl * VOCAB + v] = Sred[t] + Sred[64 + t];
        }
    }
#undef ISSUE_PF
#undef STAGE_WRITE
}

// ---------------------------------------------------------------------------
// sum: collapse 5 partial planes into one (coalesced, ~2.4 MB traffic).
// ---------------------------------------------------------------------------
__global__ __launch_bounds__(256) void sum_kernel(
    const float* __restrict__ Sp, float* __restrict__ Ss)
{
    const int v = blockIdx.x * 256 + threadIdx.x;
    if (v < VOCAB)
        Ss[v] = Sp[v] + Sp[VOCAB + v] + Sp[2 * VOCAB + v]
              + Sp[3 * VOCAB + v] + Sp[4 * VOCAB + v];
}

// ---------------------------------------------------------------------------
// attend: per token gather 20 neighbor scores, softmax, weighted emb sum.
// ---------------------------------------------------------------------------
__global__ __launch_bounds__(256) void attend_kernel(
    const int* __restrict__ text, const int* __restrict__ neighbors,
    const float* __restrict__ emb, const float* __restrict__ S,
    float* __restrict__ out)
{
    const int lane = threadIdx.x & 63;
    const int wv   = threadIdx.x >> 6;
    const int tok  = blockIdx.x * 4 + wv;

    const int tid = text[tok];

    int   nbk = 0;
    float sc  = -1e30f;
    if (lane < TOPK) {
        nbk = neighbors[tid * TOPK + lane];
        sc  = S[nbk];
    }

    float mx = sc;
#pragma unroll
    for (int m = 16; m >= 1; m >>= 1)
        mx = fmaxf(mx, __shfl_xor(mx, m));

    float ex = (lane < TOPK) ? expf(sc - mx) : 0.f;
    float sum = ex;
#pragma unroll
    for (int m = 16; m >= 1; m >>= 1)
        sum += __shfl_xor(sum, m);
    float att = ex / sum;

    float acc0 = 0.f, acc1 = 0.f, acc2 = 0.f, acc3 = 0.f, acc4 = 0.f;
    const bool has5 = (lane < EMB - 256);
#pragma unroll 4
    for (int k = 0; k < TOPK; ++k) {
        const float wgt = __shfl(att, k);
        const int   id  = __shfl(nbk, k);
        const float* row = emb + (size_t)id * EMB;
        acc0 = fmaf(wgt, row[lane      ], acc0);
        acc1 = fmaf(wgt, row[lane +  64], acc1);
        acc2 = fmaf(wgt, row[lane + 128], acc2);
        acc3 = fmaf(wgt, row[lane + 192], acc3);
        if (has5) acc4 = fmaf(wgt, row[lane + 256], acc4);
    }

    float* orow = out + (size_t)tok * EMB;
    orow[lane      ] = acc0;
    orow[lane +  64] = acc1;
    orow[lane + 128] = acc2;
    orow[lane + 192] = acc3;
    if (has5) orow[lane + 256] = acc4;
}

extern "C" void kernel_launch(void* const* d_in, const int* in_sizes, int n_in,
                              void* d_out, int out_size, void* d_ws, size_t ws_size,
                              hipStream_t stream) {
    const int*   text      = (const int*)d_in[0];
    const int*   neighbors = (const int*)d_in[1];
    const float* emb       = (const float*)d_in[2];
    const float* A         = (const float*)d_in[3];
    const float* B         = (const float*)d_in[4];
    float*       out       = (float*)d_out;

    char* ws = (char*)d_ws;
    float* Sp = (float*)ws;                 // 5 x 400,000 B partial planes
    float* Ss = (float*)(ws + 2000000);     // 400,000 B summed plane
    short* aT = (short*)(ws + 2400000);     // 204,800 B (16B-aligned)

    prep_kernel<<<320, 256, 0, stream>>>(A, aT);
    score_kernel<<<5 * NVGS, 512, 0, stream>>>(emb, aT, B, Sp);
    sum_kernel<<<(VOCAB + 255) / 256, 256, 0, stream>>>(Sp, Ss);
    attend_kernel<<<NTOK / 4, 256, 0, stream>>>(text, neighbors, emb, Ss, out);
}